// Round 7
// baseline (424.053 us; speedup 1.0000x reference)
//
#include <hip/hip_runtime.h>

// ---------------------------------------------------------------------------
// 2-layer bipartite GAT, MI355X / gfx950. Round 6 (resubmit — infra timeout):
//  - bf16 x-gather: conv_scores1 emits xbf; agg1x gathers 256B rows (was 512B)
//  - bf16 h2: gemm2 writes bf16, agg2 gathers half the bytes
//  - scanB merged into scanC (11 dispatches)
//  - (structure otherwise = round 4: no-max softmax, edge-parallel exp,
//     single-pass CSR aggregation, MFMA for both projections)
// ---------------------------------------------------------------------------

constexpr int N1 = 262144, N2 = 65536, N3 = 16384;
constexpr int E1 = 524288, E2 = 262144;
constexpr int IN_DIM = 128, HID = 64, HEADS = 4, OUT_DIM = 64;
constexpr int HD = HEADS * HID;   // 256
constexpr float NEG_SLOPE = 0.2f;
constexpr float BN_EPS = 1e-5f;

typedef __attribute__((ext_vector_type(8))) short bf16x8;
typedef __attribute__((ext_vector_type(8))) unsigned short ushort8;
typedef __attribute__((ext_vector_type(4))) float f32x4;

#define GLOAD_LDS16(gp, lp)                                              \
  __builtin_amdgcn_global_load_lds(                                      \
      (const __attribute__((address_space(1))) unsigned int*)(gp),       \
      (__attribute__((address_space(3))) unsigned int*)(lp), 16, 0, 0)

__device__ inline unsigned short f2bf(float f) {   // RNE
  unsigned u = __float_as_uint(f);
  u += 0x7FFFu + ((u >> 16) & 1u);
  return (unsigned short)(u >> 16);
}
__device__ inline float bf2f_lo(unsigned v) { return __uint_as_float(v << 16); }
__device__ inline float bf2f_hi(unsigned v) { return __uint_as_float(v & 0xffff0000u); }

// === setup: wa folds + bn folds + init + weight transposes (92 blocks) ===
__global__ __launch_bounds__(256) void setup_k(
    const float* __restrict__ W1s, const float* __restrict__ W1d,
    const float* __restrict__ A1s, const float* __restrict__ A1d,
    const float* __restrict__ W2s, const float* __restrict__ W2d,
    const float* __restrict__ A2s, const float* __restrict__ A2d,
    const float* __restrict__ b1, const float* __restrict__ gamma,
    const float* __restrict__ beta, const float* __restrict__ mean,
    const float* __restrict__ var,
    float* __restrict__ wa1s, float* __restrict__ wa1d,
    float* __restrict__ wa2s, float* __restrict__ wa2d,
    float* __restrict__ bnsc, float* __restrict__ bnsh,
    int* __restrict__ deg1, int* __restrict__ deg2,
    int* __restrict__ rp1, int* __restrict__ rp2,
    float* __restrict__ a2s, float* __restrict__ a2d,
    unsigned short* __restrict__ w1T, unsigned short* __restrict__ w2T) {
  int b = blockIdx.x, tid = threadIdx.x;
  if (b < 4) {
    int t = b * 256 + tid;
    if (t < HEADS * IN_DIM) {           // wa1 layout [h][k]
      int h = t >> 7, k = t & 127;
      float s = 0.f, d = 0.f;
      for (int c = 0; c < HID; ++c) {
        s += W1s[k * HD + h * HID + c] * A1s[h * HID + c];
        d += W1d[k * HD + h * HID + c] * A1d[h * HID + c];
      }
      wa1s[t] = s; wa1d[t] = d;
    } else if (t < HEADS * IN_DIM + HD) {
      int k = t - HEADS * IN_DIM;
      float s = 0.f, d = 0.f;
      for (int c = 0; c < OUT_DIM; ++c) {
        s += W2s[k * OUT_DIM + c] * A2s[c];
        d += W2d[k * OUT_DIM + c] * A2d[c];
      }
      wa2s[k] = s; wa2d[k] = d;
    } else if (t < HEADS * IN_DIM + 2 * HD) {
      int c = t - HEADS * IN_DIM - HD;
      float sc = gamma[c] * rsqrtf(var[c] + BN_EPS);
      bnsc[c] = sc;
      bnsh[c] = beta[c] + (b1[c] - mean[c]) * sc;
    }
  } else if (b < 68) {
    int i = (b - 4) * 256 + tid;
    int stride = 64 * 256;
    for (int j = i; j < N2; j += stride) { deg1[j] = 0; a2s[j] = 0.f; }
    for (int j = i; j < N3; j += stride) { deg2[j] = 0; a2d[j] = 0.f; }
    if (i == 0) { rp1[0] = 0; rp2[0] = 0; }
  } else if (b < 84) {
    // W1_src -> bf16 transposed [256 n][128 k], group-swizzled by n&7
    int t = (b - 68) * 256 + tid;
    int n = t >> 4, g = t & 15;
    ushort8 o;
#pragma unroll
    for (int j = 0; j < 8; ++j) o[j] = f2bf(W1s[(size_t)(g * 8 + j) * HD + n]);
    *reinterpret_cast<ushort8*>(w1T + (size_t)n * IN_DIM + (size_t)(g ^ (n & 7)) * 8) = o;
  } else {
    // W2_src -> bf16 transposed [64 n][256 k], half-swizzled by n&7
    int t = (b - 84) * 256 + tid;
    int n = t >> 5, G = t & 31;
    int k0 = G * 8;
    ushort8 o;
#pragma unroll
    for (int j = 0; j < 8; ++j) o[j] = f2bf(W2s[(size_t)(k0 + j) * OUT_DIM + n]);
    int idx = ((k0 >> 7) << 7) + ((k0 & 127) ^ ((n & 7) << 3));
    *reinterpret_cast<ushort8*>(w2T + (size_t)n * HD + idx) = o;
  }
}

// === CSR: histogram both graphs ===
__global__ __launch_bounds__(256) void hist12_k(
    const int* __restrict__ dst1, int* __restrict__ deg1, int* __restrict__ rank1,
    const int* __restrict__ dst2, int* __restrict__ deg2, int* __restrict__ rank2) {
  int b = blockIdx.x;
  if (b < E1 / 256) {
    int i = b * 256 + threadIdx.x;
    rank1[i] = atomicAdd(&deg1[dst1[i]], 1);
  } else {
    int i = (b - E1 / 256) * 256 + threadIdx.x;
    rank2[i] = atomicAdd(&deg2[dst2[i]], 1);
  }
}

// === scans (both graphs fused per stage) ===
__device__ inline void scan_body(const int* in, int* out, int* bsums, int b) {
  __shared__ int s[256];
  int tid = threadIdx.x;
  int i0 = b * 1024 + tid * 4;
  int x0 = in[i0], x1 = in[i0 + 1], x2 = in[i0 + 2], x3 = in[i0 + 3];
  int t = x0 + x1 + x2 + x3;
  s[tid] = t;
  __syncthreads();
  for (int off = 1; off < 256; off <<= 1) {
    int v = (tid >= off) ? s[tid - off] : 0;
    __syncthreads();
    s[tid] += v;
    __syncthreads();
  }
  int base = s[tid] - t;
  out[i0] = base + x0;
  out[i0 + 1] = base + x0 + x1;
  out[i0 + 2] = base + x0 + x1 + x2;
  out[i0 + 3] = base + t;
  if (tid == 255) bsums[b] = s[255];
}

__global__ __launch_bounds__(256) void scanA_k(
    const int* __restrict__ deg1, int* __restrict__ o1, int* __restrict__ bs1,
    const int* __restrict__ deg2, int* __restrict__ o2, int* __restrict__ bs2) {
  int b = blockIdx.x;
  if (b < 64) scan_body(deg1, o1, bs1, b);
  else scan_body(deg2, o2, bs2, b - 64);
}

// scanC: per-block offset = sum of preceding block sums (<=64), then add.
__global__ __launch_bounds__(256) void scanC_k(
    int* __restrict__ o1, const int* __restrict__ bs1,
    int* __restrict__ o2, const int* __restrict__ bs2) {
  __shared__ int sadd;
  int b = blockIdx.x;
  int* out; const int* bs; int bb;
  if (b < 64) { out = o1; bs = bs1; bb = b; }
  else { out = o2; bs = bs2; bb = b - 64; }
  int tid = threadIdx.x;
  if (tid < 64) {
    int v = (tid < bb) ? bs[tid] : 0;
#pragma unroll
    for (int off = 32; off; off >>= 1) v += __shfl_xor(v, off, 64);
    if (tid == 0) sadd = v;
  }
  __syncthreads();
  if (bb == 0) return;
  int add = sadd;
  int i0 = bb * 1024 + tid * 4;
  out[i0] += add; out[i0 + 1] += add; out[i0 + 2] += add; out[i0 + 3] += add;
}

// === fused: layer-1 attention scores + x -> bf16 (linear layout) ===
__global__ __launch_bounds__(256) void conv_scores1(
    const float* __restrict__ x, const float* __restrict__ wa_s,
    const float* __restrict__ wa_d, unsigned short* __restrict__ xbf,
    float* __restrict__ a_src, float* __restrict__ a_dst) {
  __shared__ float ws[HEADS * IN_DIM], wd[HEADS * IN_DIM];
  int tid = threadIdx.x;
  for (int i = tid; i < HEADS * IN_DIM; i += 256) { ws[i] = wa_s[i]; wd[i] = wa_d[i]; }
  __syncthreads();
  int row = blockIdx.x * 16 + (tid >> 4);
  int g = tid & 15;
  float4 v0 = *reinterpret_cast<const float4*>(x + (size_t)row * IN_DIM + g * 8);
  float4 v1 = *reinterpret_cast<const float4*>(x + (size_t)row * IN_DIM + g * 8 + 4);
  float xv[8] = {v0.x, v0.y, v0.z, v0.w, v1.x, v1.y, v1.z, v1.w};
  ushort8 o;
#pragma unroll
  for (int j = 0; j < 8; ++j) o[j] = f2bf(xv[j]);
  *reinterpret_cast<ushort8*>(xbf + (size_t)row * IN_DIM + g * 8) = o;
#pragma unroll
  for (int h = 0; h < HEADS; ++h) {
    float p = 0.f;
#pragma unroll
    for (int j = 0; j < 8; ++j) p = fmaf(xv[j], ws[h * IN_DIM + g * 8 + j], p);
#pragma unroll
    for (int off = 1; off < 16; off <<= 1) p += __shfl_xor(p, off, 64);
    if (g == 0) a_src[(size_t)row * HEADS + h] = p;
  }
  if (row < N2) {
#pragma unroll
    for (int h = 0; h < HEADS; ++h) {
      float p = 0.f;
#pragma unroll
      for (int j = 0; j < 8; ++j) p = fmaf(xv[j], wd[h * IN_DIM + g * 8 + j], p);
#pragma unroll
      for (int off = 1; off < 16; off <<= 1) p += __shfl_xor(p, off, 64);
      if (g == 0) a_dst[(size_t)row * HEADS + h] = p;
    }
  }
}

// === CSR scatter + edge weight p = exp(leaky(e)) (layer 1, 4 heads) ===
__global__ __launch_bounds__(256) void scatter1p_k(
    const int* __restrict__ src, const int* __restrict__ dst,
    const int* __restrict__ rp, const int* __restrict__ rank,
    const float* __restrict__ a1s, const float* __restrict__ a1d,
    int* __restrict__ srcs, float4* __restrict__ pexp) {
  int i = blockIdx.x * 256 + threadIdx.x;
  int s = src[i], d = dst[i];
  float4 as = *reinterpret_cast<const float4*>(a1s + (size_t)s * HEADS);
  float4 ad = *reinterpret_cast<const float4*>(a1d + (size_t)d * HEADS);
  float4 p;
#pragma unroll
  for (int h = 0; h < 4; ++h) {
    float e = ((const float*)&as)[h] + ((const float*)&ad)[h];
    e = e > 0.f ? e : NEG_SLOPE * e;
    ((float*)&p)[h] = __expf(e);
  }
  int pos = rp[d] + rank[i];
  srcs[pos] = s;
  pexp[pos] = p;
}

// === layer-1 aggregation: wave per dst (all 4 heads), single pass, no shfl.
//     gathers bf16 x rows (256B); z[h][N2][128] bf16, group-swizzled (d&7) ===
__global__ __launch_bounds__(256) void agg1x(
    const int* __restrict__ rp, const int* __restrict__ srcs,
    const float4* __restrict__ pexp, const unsigned short* __restrict__ xbf,
    unsigned short* __restrict__ z) {
  int d = blockIdx.x * 4 + (threadIdx.x >> 6);
  int lane = threadIdx.x & 63;
  int beg = rp[d], end = rp[d + 1];
  float z0[4] = {0.f, 0.f, 0.f, 0.f}, z1[4] = {0.f, 0.f, 0.f, 0.f};
  float ss[4] = {0.f, 0.f, 0.f, 0.f}, ss2[4] = {0.f, 0.f, 0.f, 0.f};
  int j = beg;
  for (; j + 2 <= end; j += 2) {
    int s0 = srcs[j], s1 = srcs[j + 1];
    float4 p0 = pexp[j], p1 = pexp[j + 1];
    unsigned u0 = ((const unsigned*)(xbf + (size_t)s0 * IN_DIM))[lane];
    unsigned u1 = ((const unsigned*)(xbf + (size_t)s1 * IN_DIM))[lane];
    float v0x = bf2f_lo(u0), v0y = bf2f_hi(u0);
    float v1x = bf2f_lo(u1), v1y = bf2f_hi(u1);
#pragma unroll
    for (int h = 0; h < 4; ++h) {
      float ph0 = ((const float*)&p0)[h], ph1 = ((const float*)&p1)[h];
      z0[h] = fmaf(ph0, v0x, fmaf(ph1, v1x, z0[h]));
      z1[h] = fmaf(ph0, v0y, fmaf(ph1, v1y, z1[h]));
      ss[h] += ph0; ss2[h] += ph1;
    }
  }
  if (j < end) {
    int s0 = srcs[j];
    float4 p0 = pexp[j];
    unsigned u0 = ((const unsigned*)(xbf + (size_t)s0 * IN_DIM))[lane];
    float v0x = bf2f_lo(u0), v0y = bf2f_hi(u0);
#pragma unroll
    for (int h = 0; h < 4; ++h) {
      float ph0 = ((const float*)&p0)[h];
      z0[h] = fmaf(ph0, v0x, z0[h]);
      z1[h] = fmaf(ph0, v0y, z1[h]);
      ss[h] += ph0;
    }
  }
  int G = lane >> 2;
  int idx = ((G ^ (d & 7)) << 3) + ((lane & 3) << 1);
#pragma unroll
  for (int h = 0; h < 4; ++h) {
    float inv = 1.f / fmaxf(ss[h] + ss2[h], 1e-30f);
    unsigned out = (unsigned)f2bf(z0[h] * inv) | ((unsigned)f2bf(z1[h] * inv) << 16);
    *reinterpret_cast<unsigned*>(z + ((size_t)h * N2 + d) * IN_DIM + idx) = out;
  }
}

// === finalize layer 1: acc1 = ELU(BN(z_h @ W1_h)) via MFMA; fused layer-2
//     attention partial dots (atomicAdd). acc1 bf16, half-swizzled. ===
__global__ __launch_bounds__(256) void finalize1(
    const unsigned short* __restrict__ z, const unsigned short* __restrict__ w1T,
    const float* __restrict__ bnsc, const float* __restrict__ bnsh,
    const float* __restrict__ wa2s, const float* __restrict__ wa2d,
    unsigned short* __restrict__ acc1, float* __restrict__ a2s,
    float* __restrict__ a2d) {
  __shared__ char sm[49152];   // A: 32 KB @0, B: 16 KB @32768
  const int tid = threadIdx.x, wave = tid >> 6, lane = tid & 63;
  const int row0 = blockIdx.x * 128;
  const int h = blockIdx.y;
  const char* gA = (const char*)(z + ((size_t)h * N2 + row0) * IN_DIM);
  const char* gB = (const char*)(w1T + (size_t)h * 64 * IN_DIM);
#pragma unroll
  for (int it = 0; it < 8; ++it) {
    int off = it * 4096 + wave * 1024 + lane * 16;
    GLOAD_LDS16(gA + off, sm + off);
  }
#pragma unroll
  for (int it = 0; it < 4; ++it) {
    int off = it * 4096 + wave * 1024 + lane * 16;
    GLOAD_LDS16(gB + off, sm + 32768 + off);
  }
  __syncthreads();
  const int rbase = wave * 32;
  const int kl = (lane >> 4) * 8, fr = lane & 15;
  f32x4 acc[2][4] = {};
#pragma unroll
  for (int ks = 0; ks < 4; ++ks) {
    int k0 = ks * 32 + kl;
    bf16x8 a[2], b[4];
#pragma unroll
    for (int i = 0; i < 2; ++i) {
      int ra = rbase + i * 16 + fr;
      a[i] = *reinterpret_cast<const bf16x8*>(
          sm + ((size_t)ra * 128 + (k0 ^ ((ra & 7) << 3))) * 2);
    }
#pragma unroll
    for (int jj = 0; jj < 4; ++jj) {
      int cb = jj * 16 + fr;
      b[jj] = *reinterpret_cast<const bf16x8*>(
          sm + 32768 + ((size_t)cb * 128 + (k0 ^ ((cb & 7) << 3))) * 2);
    }
#pragma unroll
    for (int i = 0; i < 2; ++i)
#pragma unroll
      for (int jj = 0; jj < 4; ++jj)
        acc[i][jj] = __builtin_amdgcn_mfma_f32_16x16x32_bf16(a[i], b[jj], acc[i][jj], 0, 0, 0);
  }
  float sc[4], sh[4], w2sv[4], w2dv[4];
#pragma unroll
  for (int jj = 0; jj < 4; ++jj) {
    int c = h * 64 + jj * 16 + fr;
    sc[jj] = bnsc[c]; sh[jj] = bnsh[c]; w2sv[jj] = wa2s[c]; w2dv[jj] = wa2d[c];
  }
  const int g = lane >> 4;
#pragma unroll
  for (int i = 0; i < 2; ++i) {
#pragma unroll
    for (int q = 0; q < 4; ++q) {
      int row = row0 + rbase + i * 16 + g * 4 + q;
      float s2s = 0.f, s2d = 0.f;
#pragma unroll
      for (int jj = 0; jj < 4; ++jj) {
        float v = acc[i][jj][q] * sc[jj] + sh[jj];
        v = v > 0.f ? v : expm1f(v);
        s2s = fmaf(v, w2sv[jj], s2s);
        s2d = fmaf(v, w2dv[jj], s2d);
        int c = h * 64 + jj * 16 + fr;
        int idx = ((c >> 7) << 7) + ((c & 127) ^ ((row & 7) << 3));
        acc1[(size_t)row * HD + idx] = f2bf(v);
      }
#pragma unroll
      for (int off = 1; off < 16; off <<= 1) {
        s2s += __shfl_xor(s2s, off, 64);
        s2d += __shfl_xor(s2d, off, 64);
      }
      if (fr == 0) {
        atomicAdd(&a2s[row], s2s);
        if (row < N3) atomicAdd(&a2d[row], s2d);
      }
    }
  }
}

// === CSR scatter + p (layer 2, 1 head) — runs after finalize1 ===
__global__ __launch_bounds__(256) void scatter2p_k(
    const int* __restrict__ src, const int* __restrict__ dst,
    const int* __restrict__ rp, const int* __restrict__ rank,
    const float* __restrict__ a2s, const float* __restrict__ a2d,
    int* __restrict__ srcs, float* __restrict__ pexp) {
  int i = blockIdx.x * 256 + threadIdx.x;
  int s = src[i], d = dst[i];
  float e = a2s[s] + a2d[d];
  e = e > 0.f ? e : NEG_SLOPE * e;
  int pos = rp[d] + rank[i];
  srcs[pos] = s;
  pexp[pos] = __expf(e);
}

// === layer-2 GEMM: h2bf[N2][64] = acc1_bf16 @ W2sT^T (bf16 out) ===
__global__ __launch_bounds__(256) void gemm2(
    const unsigned short* __restrict__ acc1, const unsigned short* __restrict__ w2T,
    unsigned short* __restrict__ h2bf) {
  __shared__ char sm[65536];
  const int tid = threadIdx.x, wave = tid >> 6, lane = tid & 63;
  const int row0 = blockIdx.x * 128;
  const char* gB = (const char*)w2T;
#pragma unroll
  for (int it = 0; it < 8; ++it) {
    int off = it * 4096 + wave * 1024 + lane * 16;
    GLOAD_LDS16(gB + off, sm + 32768 + off);
  }
  const int rbase = wave * 32;
  const int kl = (lane >> 4) * 8, fr = lane & 15;
  f32x4 acc[2][4] = {};
  for (int kh = 0; kh < 2; ++kh) {
    __syncthreads();
#pragma unroll
    for (int it = 0; it < 8; ++it) {
      int r = it * 16 + (tid >> 4);
      const char* srcp = (const char*)(acc1 + (size_t)(row0 + r) * HD) +
                         kh * 256 + (tid & 15) * 16;
      GLOAD_LDS16(srcp, sm + it * 4096 + tid * 16);
    }
    __syncthreads();
#pragma unroll
    for (int ks = 0; ks < 4; ++ks) {
      int k0 = ks * 32 + kl;
      bf16x8 a[2], b[4];
#pragma unroll
      for (int i = 0; i < 2; ++i) {
        int ra = rbase + i * 16 + fr;
        a[i] = *reinterpret_cast<const bf16x8*>(
            sm + ((size_t)ra * 128 + (k0 ^ ((ra & 7) << 3))) * 2);
      }
#pragma unroll
      for (int jj = 0; jj < 4; ++jj) {
        int cb = jj * 16 + fr;
        b[jj] = *reinterpret_cast<const bf16x8*>(
            sm + 32768 + ((size_t)cb * 256 + kh * 128 + (k0 ^ ((cb & 7) << 3))) * 2);
      }
#pragma unroll
      for (int i = 0; i < 2; ++i)
#pragma unroll
        for (int jj = 0; jj < 4; ++jj)
          acc[i][jj] = __builtin_amdgcn_mfma_f32_16x16x32_bf16(a[i], b[jj], acc[i][jj], 0, 0, 0);
    }
  }
  const int g = lane >> 4;
#pragma unroll
  for (int i = 0; i < 2; ++i)
#pragma unroll
    for (int q = 0; q < 4; ++q) {
      int row = row0 + rbase + i * 16 + g * 4 + q;
#pragma unroll
      for (int jj = 0; jj < 4; ++jj)
        h2bf[(size_t)row * OUT_DIM + jj * 16 + fr] = f2bf(acc[i][jj][q]);
    }
}

// === layer-2 aggregation: wave per dst, single pass, writes d_out ===
__global__ __launch_bounds__(256) void agg2(
    const int* __restrict__ rp, const int* __restrict__ srcs,
    const float* __restrict__ pe, const unsigned short* __restrict__ h2bf,
    const float* __restrict__ b2, float* __restrict__ out) {
  int d = blockIdx.x * 4 + (threadIdx.x >> 6);
  int lane = threadIdx.x & 63;
  int beg = rp[d], end = rp[d + 1];
  float ssum = 0.f, ssum2 = 0.f, acc = 0.f, acc2 = 0.f;
  int j = beg;
  for (; j + 2 <= end; j += 2) {
    int s0 = srcs[j], s1 = srcs[j + 1];
    float p0 = pe[j], p1 = pe[j + 1];
    float v0 = __uint_as_float((unsigned)h2bf[(size_t)s0 * OUT_DIM + lane] << 16);
    float v1 = __uint_as_float((unsigned)h2bf[(size_t)s1 * OUT_DIM + lane] << 16);
    acc = fmaf(p0, v0, acc); acc2 = fmaf(p1, v1, acc2);
    ssum += p0; ssum2 += p1;
  }
  if (j < end) {
    int s0 = srcs[j];
    float p0 = pe[j];
    float v0 = __uint_as_float((unsigned)h2bf[(size_t)s0 * OUT_DIM + lane] << 16);
    acc = fmaf(p0, v0, acc);
    ssum += p0;
  }
  acc += acc2; ssum += ssum2;
  out[(size_t)d * OUT_DIM + lane] = acc / fmaxf(ssum, 1e-30f) + b2[lane];
}

extern "C" void kernel_launch(void* const* d_in, const int* in_sizes, int n_in,
                              void* d_out, int out_size, void* d_ws, size_t ws_size,
                              hipStream_t stream) {
  const float* x     = (const float*)d_in[0];
  const float* W1s   = (const float*)d_in[1];
  const float* W1d   = (const float*)d_in[2];
  const float* A1s   = (const float*)d_in[3];
  const float* A1d   = (const float*)d_in[4];
  const float* b1    = (const float*)d_in[5];
  const float* gamma = (const float*)d_in[6];
  const float* beta  = (const float*)d_in[7];
  const float* rmean = (const float*)d_in[8];
  const float* rvar  = (const float*)d_in[9];
  const float* W2s   = (const float*)d_in[10];
  const float* W2d   = (const float*)d_in[11];
  const float* A2s   = (const float*)d_in[12];
  const float* A2d   = (const float*)d_in[13];
  const float* b2    = (const float*)d_in[14];
  const int* src1    = (const int*)d_in[15];
  const int* dst1    = (const int*)d_in[16];
  const int* src2    = (const int*)d_in[17];
  const int* dst2    = (const int*)d_in[18];
  (void)in_sizes; (void)n_in; (void)out_size; (void)ws_size;

  char* W = (char*)d_ws;
  size_t off = 0;
  auto alloc = [&](size_t bytes) { void* p = W + off; off = (off + bytes + 255) & ~(size_t)255; return p; };
  unsigned short* xbf  = (unsigned short*)alloc((size_t)N1 * IN_DIM * 2);
  unsigned short* z    = (unsigned short*)alloc((size_t)HEADS * N2 * IN_DIM * 2);
  unsigned short* w1T  = (unsigned short*)alloc((size_t)HD * IN_DIM * 2);
  unsigned short* w2T  = (unsigned short*)alloc((size_t)OUT_DIM * HD * 2);
  unsigned short* acc1 = (unsigned short*)alloc((size_t)N2 * HD * 2);
  unsigned short* h2bf = (unsigned short*)alloc((size_t)N2 * OUT_DIM * 2);
  float* a1s   = (float*)alloc((size_t)N1 * HEADS * 4);
  float* a1d   = (float*)alloc((size_t)N2 * HEADS * 4);
  float* a2s   = (float*)alloc((size_t)N2 * 4);
  float* a2d   = (float*)alloc((size_t)N3 * 4);
  float4* pexp1 = (float4*)alloc((size_t)E1 * 16);
  float* pexp2 = (float*)alloc((size_t)E2 * 4);
  int* deg1    = (int*)alloc((size_t)N2 * 4);
  int* rank1   = (int*)alloc((size_t)E1 * 4);
  int* rp1     = (int*)alloc((size_t)(N2 + 1) * 4);
  int* srcs1   = (int*)alloc((size_t)E1 * 4);
  int* deg2    = (int*)alloc((size_t)N3 * 4);
  int* rank2   = (int*)alloc((size_t)E2 * 4);
  int* rp2     = (int*)alloc((size_t)(N3 + 1) * 4);
  int* srcs2   = (int*)alloc((size_t)E2 * 4);
  float* wa1s  = (float*)alloc(HEADS * IN_DIM * 4);
  float* wa1d  = (float*)alloc(HEADS * IN_DIM * 4);
  float* wa2s  = (float*)alloc(HD * 4);
  float* wa2d  = (float*)alloc(HD * 4);
  float* bnsc  = (float*)alloc(HD * 4);
  float* bnsh  = (float*)alloc(HD * 4);
  int* bsums1  = (int*)alloc(64 * 4);
  int* bsums2  = (int*)alloc(64 * 4);

  setup_k<<<92, 256, 0, stream>>>(W1s, W1d, A1s, A1d, W2s, W2d, A2s, A2d,
                                  b1, gamma, beta, rmean, rvar,
                                  wa1s, wa1d, wa2s, wa2d, bnsc, bnsh,
                                  deg1, deg2, rp1, rp2, a2s, a2d, w1T, w2T);
  hist12_k<<<E1 / 256 + E2 / 256, 256, 0, stream>>>(dst1, deg1, rank1,
                                                    dst2, deg2, rank2);
  scanA_k<<<80, 256, 0, stream>>>(deg1, rp1 + 1, bsums1, deg2, rp2 + 1, bsums2);
  scanC_k<<<80, 256, 0, stream>>>(rp1 + 1, bsums1, rp2 + 1, bsums2);

  // ---- layer 1 ----
  conv_scores1<<<N1 / 16, 256, 0, stream>>>(x, wa1s, wa1d, xbf, a1s, a1d);
  scatter1p_k<<<E1 / 256, 256, 0, stream>>>(src1, dst1, rp1, rank1, a1s, a1d,
                                            srcs1, pexp1);
  agg1x<<<N2 / 4, 256, 0, stream>>>(rp1, srcs1, pexp1, xbf, z);
  finalize1<<<dim3(N2 / 128, HEADS), 256, 0, stream>>>(
      z, w1T, bnsc, bnsh, wa2s, wa2d, acc1, a2s, a2d);

  // ---- layer 2 ----
  scatter2p_k<<<E2 / 256, 256, 0, stream>>>(src2, dst2, rp2, rank2, a2s, a2d,
                                            srcs2, pexp2);
  gemm2<<<N2 / 128, 256, 0, stream>>>(acc1, w2T, h2bf);
  agg2<<<N3 / 4, 256, 0, stream>>>(rp2, srcs2, pexp2, h2bf, b2, (float*)d_out);
}